// Round 10
// baseline (48.103 us; speedup 1.0000x reference)
//
#include <hip/hip_runtime.h>
#include <hip/hip_bf16.h>
#include <math.h>

// ThickCubeSimulator R9: DIAGNOSTIC round (deliberate ~2x deposit).
//  Four rounds of model-vs-measurement mismatch on the deposit (~20us by
//  elimination, ~2-3us by static issue math). The rocprof top-5 is saturated
//  by ~39us harness fills, hiding all our kernels. This round runs the
//  deposit TWICE in a standalone kernel (atomics double H, write-out x0.5 --
//  numerically exact) so it crosses the ~39.5us visibility threshold and we
//  get VALUBusy / SQ_LDS_BANK_CONFLICT / Occupancy for a pure-deposit
//  workload. gtable + matvec are R7's proven phases.

#define RES   80
#define NB    160
#define NBP   161
#define NM    40
#define H4P   164        // padded per-pixel H stride (16B-aligned b128 reads)
#define NPIXT (RES*RES)
#define NPIXB 4          // coarse pixels per block
#define C_KMS 299792.458f
#define F0GHZ 230.538f
#define LOG2E 1.44269504088896340736f
#define HPI   1.57079632679489662f
#define VBIN0 -198.75f
#define VBINW 2.5f

// ws layout (bytes): prm floats | GT[b][M] | H[pix][b] (padded)
#define PRM_OFF 0
#define GT_OFF  128
#define H_OFF   32768
#define WS_REQ  (H_OFF + (size_t)NPIXT * H4P * 4)

__device__ __forceinline__ float fast_exp2(float x) {
#if __has_builtin(__builtin_amdgcn_exp2f)
  return __builtin_amdgcn_exp2f(x);
#else
  return exp2f(x);
#endif
}
__device__ __forceinline__ float fast_rcp(float x) {
#if __has_builtin(__builtin_amdgcn_rcpf)
  return __builtin_amdgcn_rcpf(x);
#else
  return 1.0f / x;
#endif
}

// atan(u) for u>=0 via t=min(u,1/u) in [0,1], poly err ~1e-6 rad
__device__ __forceinline__ float atan_pos(float u, float uinv) {
  const float t  = fminf(u, uinv);
  const float t2 = t * t;
  float p = fmaf(t2, -0.0117212f, 0.05265332f);
  p = fmaf(t2, p, -0.11643287f);
  p = fmaf(t2, p, 0.19354346f);
  p = fmaf(t2, p, -0.33262347f);
  p = fmaf(t2, p, 0.99997726f);
  const float a = t * p;
  return (u <= 1.0f) ? a : (HPI - a);
}

// ---- k1: GT table (transposed: GT[b*NM + M]) + params ----
__global__ __launch_bounds__(256) void gtable_kernel(
    const float* __restrict__ p_inc, const float* __restrict__ p_rot,
    const float* __restrict__ p_lb,  const float* __restrict__ p_vs,
    const float* __restrict__ p_vmax, const float* __restrict__ p_rturn,
    const float* __restrict__ p_i0,  const float* __restrict__ p_rd,
    const float* __restrict__ freqs, float* __restrict__ ws)
{
  float* gt = ws + GT_OFF / 4;
  const int e = blockIdx.x * 256 + threadIdx.x;
  if (e < NB * NM) {
    const int b = e / NM;
    const int M = e - b * NM;
    const float sig    = p_lb[0];
    const float vshift = p_vs[0];
    const float fc0    = freqs[0];
    const float fc1    = freqs[1];
    const float c2l    = -0.5f * LOG2E / (sig * sig);
    const float norm16 = 0.3989422804014327f / sig * 0.0625f;
    const float df = (fc1 - fc0) * 0.25f;
    const float f0 = fc0 - 1.5f * df;
    const float vbin = VBIN0 + VBINW * (float)b;
    float s = 0.f;
    #pragma unroll
    for (int r = 0; r < 4; ++r) {
      const float ffine = f0 + df * (float)(4 * M + r);
      const float vlab  = C_KMS * (F0GHZ - ffine) / F0GHZ - vshift;
      const float d = vlab - vbin;
      s += fast_exp2(c2l * d * d);
    }
    gt[e] = s * norm16;
  }
  if (blockIdx.x == 0 && threadIdx.x == 0) {
    const float inc = p_inc[0], rot = p_rot[0];
    const float si = sinf(inc);
    float* prm = ws + PRM_OFF / 4;
    prm[0] = cosf(inc);                              // ci
    prm[1] = si;                                     // si
    prm[2] = cosf(rot);                              // cr
    prm[3] = sinf(rot);                              // sr
    prm[4] = -p_vmax[0] * 0.63661977236758134f * si; // kfac
    prm[5] = 1.0f / p_rturn[0];                      // irt
    prm[6] = p_rturn[0];                             // rt
    prm[7] = -LOG2E / p_rd[0];                       // crd
    prm[8] = __log2f(p_i0[0]);                       // li0
    prm[9] = 1.0f / VBINW;                           // invw
    prm[10] = -VBIN0 / VBINW;                        // boff
  }
}

// per-cell math -> (UO = bin coordinate, IO = intensity); independent chain
#define CELL(kk, UO, IO) {                                  \
    const float gz = -993.75f + 12.5f * (float)(kk);        \
    const float ry = fmaf(-si, gz, y1ci);                   \
    const float s2 = fmaf(ry, ry, x12);                     \
    const float rq = sqrtf(s2);                             \
    const float ri = fast_rcp(fmaxf(rq, 1e-30f));           \
    const float at = atan_pos(rq * irt, rt * ri);           \
    const float rs = sqrtf(fmaf(gz, gz, gxy2));             \
    UO = fmaf(kcol * (ri * at), invw, boff);                \
    IO = fast_exp2(fmaf(rs, crd, li0)); }

// run-length CIC merge of one (uu, inten) into (cb, a0, a1); flush on change
#define MERGE(uu, inten) {                                  \
    const int   bi = (int)(uu);                             \
    const float w1 = (inten) * ((uu) - (float)bi);          \
    const float w0 = (inten) - w1;                          \
    if (bi == cb)          { a0 += w0; a1 += w1; }          \
    else if (bi == cb + 1) { unsafeAtomicAdd(&Hc[cb], a0);  \
                             a0 = a1 + w0; a1 = w1; cb = bi; } \
    else { unsafeAtomicAdd(&Hc[cb], a0);                    \
           unsafeAtomicAdd(&Hc[cb + 1], a1);                \
           a0 = w0; a1 = w1; cb = bi; } }

// ---- k2: deposit x2 (diagnostic doubling; write-out x0.5 is exact) ----
__global__ __launch_bounds__(256, 6) void deposit2x_kernel(
    const float* __restrict__ ws_prm, float* __restrict__ h)
{
  __shared__ float Hs[16 * NBP];                  // 16 sub-hists, 10304 B
  const int t   = threadIdx.x;
  const int blk = blockIdx.x;                     // 0..1599
  const int p   = blk / (RES / NPIXB);
  const int q0  = (blk - p * (RES / NPIXB)) * NPIXB;

  const float* prm = ws_prm;
  const float ci = prm[0], si = prm[1], cr = prm[2], sr = prm[3];
  const float kfac = prm[4], irt = prm[5], rt = prm[6], crd = prm[7];
  const float li0 = prm[8], invw = prm[9], boff = prm[10];

  for (int e = t; e < 16 * NBP; e += 256) Hs[e] = 0.f;
  __syncthreads();

  {
    const int pix = t >> 6;          // 0..3 (wave-uniform)
    const int col = (t >> 4) & 3;    // fine 2x2 pixel
    const int seg = t & 15;          // 10-z segment
    const int i   = 2 * p + (col >> 1);
    const int j   = 2 * (q0 + pix) + (col & 1);
    const float gx = -993.75f + 12.5f * (float)i;
    const float gy = -993.75f + 12.5f * (float)j;
    const float x1 = gx * cr - gy * sr;
    const float y1 = gx * sr + gy * cr;
    const float x12  = x1 * x1;
    const float gxy2 = gx * gx + gy * gy;
    const float y1ci = y1 * ci;
    const float kcol = kfac * x1;
    float* Hc = &Hs[(pix * 4 + col) * NBP];
    const int k0 = seg * 10;

    #pragma unroll 1
    for (int round = 0; round < 2; ++round) {   // <-- 2x deposit (diagnostic)
      float U[5], I[5];
      int cb; float a0, a1;
      #pragma unroll
      for (int c = 0; c < 5; ++c) CELL(k0 + c, U[c], I[c])
      { const int bi = (int)U[0];
        const float w1 = I[0] * (U[0] - (float)bi);
        cb = bi; a0 = I[0] - w1; a1 = w1; }
      #pragma unroll
      for (int c = 1; c < 5; ++c) MERGE(U[c], I[c])
      #pragma unroll
      for (int c = 0; c < 5; ++c) CELL(k0 + 5 + c, U[c], I[c])
      #pragma unroll
      for (int c = 0; c < 5; ++c) MERGE(U[c], I[c])
      unsafeAtomicAdd(&Hc[cb],     a0);
      unsafeAtomicAdd(&Hc[cb + 1], a1);
    }
  }
  __syncthreads();

  // reduce 4 sub-hists -> per-pixel row, x0.5 (undo the doubling), pad zero
  for (int e = t; e < NPIXB * H4P; e += 256) {
    const int v  = e / H4P;
    const int bb = e - v * H4P;
    float s = 0.f;
    if (bb < NB) {
      s = 0.5f * ((Hs[(v * 4 + 0) * NBP + bb] + Hs[(v * 4 + 1) * NBP + bb])
                + (Hs[(v * 4 + 2) * NBP + bb] + Hs[(v * 4 + 3) * NBP + bb]));
    }
    h[(size_t)(p * RES + q0 + v) * H4P + bb] = s;
  }
}

// ---- k3: matvec (R7 structure, H from ws) ----
__global__ __launch_bounds__(256) void matvec_kernel(
    const float* __restrict__ ws, const float* __restrict__ h,
    float* __restrict__ out)
{
  __shared__ __align__(16) float H4[NPIXB * H4P]; // 2624 B
  __shared__ float Pp[16 * NM];                   // 2560 B
  const int t   = threadIdx.x;
  const int blk = blockIdx.x;                     // 0..1599
  const int p   = blk / (RES / NPIXB);
  const int q0  = (blk - p * (RES / NPIXB)) * NPIXB;

  const float4* hsrc = (const float4*)(h + (size_t)(p * RES + q0) * H4P);
  for (int e = t; e < NPIXB * H4P / 4; e += 256)
    ((float4*)H4)[e] = hsrc[e];
  __syncthreads();

  const int w = t >> 6;
  const int l = t & 63;
  if (l < NM) {
    const float* G = ws + GT_OFF / 4 + l;   // + b*NM per bin
    const int b0w = w * 40;
    float acc[NPIXB] = {0.f, 0.f, 0.f, 0.f};
    #pragma unroll
    for (int c4 = 0; c4 < 10; ++c4) {
      const int b0 = b0w + c4 * 4;
      const float g0 = G[(b0 + 0) * NM];
      const float g1 = G[(b0 + 1) * NM];
      const float g2 = G[(b0 + 2) * NM];
      const float g3 = G[(b0 + 3) * NM];
      #pragma unroll
      for (int pix = 0; pix < NPIXB; ++pix) {
        const float4 hh = *(const float4*)&H4[pix * H4P + b0];
        acc[pix] = fmaf(hh.x, g0, fmaf(hh.y, g1,
                   fmaf(hh.z, g2, fmaf(hh.w, g3, acc[pix]))));
      }
    }
    #pragma unroll
    for (int pix = 0; pix < NPIXB; ++pix)
      Pp[(w * NPIXB + pix) * NM + l] = acc[pix];
  }
  __syncthreads();

  if (t < NPIXB * NM) {
    const int m   = t >> 2;
    const int pix = t & 3;
    const float s = (Pp[(0 * NPIXB + pix) * NM + m] +
                     Pp[(1 * NPIXB + pix) * NM + m]) +
                    (Pp[(2 * NPIXB + pix) * NM + m] +
                     Pp[(3 * NPIXB + pix) * NM + m]);
    out[(size_t)m * NPIXT + p * RES + q0 + pix] = s;
  }
}

// ---- fallback (tiny ws): single fused kernel, deposit once + on-the-fly G ----
__global__ __launch_bounds__(256, 4) void fused_self_kernel(
    const float* __restrict__ p_inc, const float* __restrict__ p_rot,
    const float* __restrict__ p_lb,  const float* __restrict__ p_vs,
    const float* __restrict__ p_vmax, const float* __restrict__ p_rturn,
    const float* __restrict__ p_i0,  const float* __restrict__ p_rd,
    const float* __restrict__ freqs, float* __restrict__ out)
{
  __shared__ float Hs[16 * NBP];
  __shared__ __align__(16) float H4[NPIXB * H4P];
  __shared__ float Pp[16 * NM];
  const int t   = threadIdx.x;
  const int blk = blockIdx.x;
  const int p   = blk / (RES / NPIXB);
  const int q0  = (blk - p * (RES / NPIXB)) * NPIXB;

  const float inc = p_inc[0], rotv = p_rot[0], sig = p_lb[0];
  const float si = sinf(inc), ci = cosf(inc);
  const float cr = cosf(rotv), sr = sinf(rotv);
  const float kfac = -p_vmax[0] * 0.63661977236758134f * si;
  const float rt   = p_rturn[0];
  const float irt  = 1.0f / rt;
  const float crd  = -LOG2E / p_rd[0];
  const float li0  = __log2f(p_i0[0]);
  const float invw = 1.0f / VBINW;
  const float boff = -VBIN0 / VBINW;
  const float c2l    = -0.5f * LOG2E / (sig * sig);
  const float norm16 = 0.3989422804014327f / sig * 0.0625f;
  const float df     = (freqs[1] - freqs[0]) * 0.25f;
  const float f0     = freqs[0] - 1.5f * df;
  const float vshift = p_vs[0];

  for (int e = t; e < 16 * NBP; e += 256) Hs[e] = 0.f;
  __syncthreads();
  {
    const int pix = t >> 6;
    const int col = (t >> 4) & 3;
    const int seg = t & 15;
    const int i   = 2 * p + (col >> 1);
    const int j   = 2 * (q0 + pix) + (col & 1);
    const float gx = -993.75f + 12.5f * (float)i;
    const float gy = -993.75f + 12.5f * (float)j;
    const float x1 = gx * cr - gy * sr;
    const float y1 = gx * sr + gy * cr;
    const float x12  = x1 * x1;
    const float gxy2 = gx * gx + gy * gy;
    const float y1ci = y1 * ci;
    const float kcol = kfac * x1;
    float* Hc = &Hs[(pix * 4 + col) * NBP];
    const int k0 = seg * 10;
    float U[5], I[5];
    int cb; float a0, a1;
    #pragma unroll
    for (int c = 0; c < 5; ++c) CELL(k0 + c, U[c], I[c])
    { const int bi = (int)U[0];
      const float w1 = I[0] * (U[0] - (float)bi);
      cb = bi; a0 = I[0] - w1; a1 = w1; }
    #pragma unroll
    for (int c = 1; c < 5; ++c) MERGE(U[c], I[c])
    #pragma unroll
    for (int c = 0; c < 5; ++c) CELL(k0 + 5 + c, U[c], I[c])
    #pragma unroll
    for (int c = 0; c < 5; ++c) MERGE(U[c], I[c])
    unsafeAtomicAdd(&Hc[cb],     a0);
    unsafeAtomicAdd(&Hc[cb + 1], a1);
  }
  __syncthreads();
  for (int e = t; e < NPIXB * NB; e += 256) {
    const int v = e / NB;
    const int b = e - v * NB;
    H4[v * H4P + b] = (Hs[(v * 4 + 0) * NBP + b] + Hs[(v * 4 + 1) * NBP + b])
                    + (Hs[(v * 4 + 2) * NBP + b] + Hs[(v * 4 + 3) * NBP + b]);
  }
  __syncthreads();
  {
    const int w = t >> 6;
    const int l = t & 63;
    if (l < NM) {
      float vlab[4];
      #pragma unroll
      for (int r = 0; r < 4; ++r) {
        const float ffine = f0 + df * (float)(4 * l + r);
        vlab[r] = C_KMS * (F0GHZ - ffine) / F0GHZ - vshift;
      }
      float acc[NPIXB] = {0.f, 0.f, 0.f, 0.f};
      const int b0w = w * 40;
      for (int c4 = 0; c4 < 10; ++c4) {
        const int b0 = b0w + c4 * 4;
        float g[4];
        #pragma unroll
        for (int s = 0; s < 4; ++s) {
          const float vbin = VBIN0 + VBINW * (float)(b0 + s);
          float sg = 0.f;
          #pragma unroll
          for (int r = 0; r < 4; ++r) {
            const float d = vlab[r] - vbin;
            sg += fast_exp2(c2l * d * d);
          }
          g[s] = sg;
        }
        #pragma unroll
        for (int pix = 0; pix < NPIXB; ++pix) {
          const float4 hh = *(const float4*)&H4[pix * H4P + b0];
          acc[pix] = fmaf(hh.x, g[0], fmaf(hh.y, g[1],
                     fmaf(hh.z, g[2], fmaf(hh.w, g[3], acc[pix]))));
        }
      }
      #pragma unroll
      for (int pix = 0; pix < NPIXB; ++pix)
        Pp[(w * NPIXB + pix) * NM + l] = acc[pix] * norm16;
    }
  }
  __syncthreads();
  if (t < NPIXB * NM) {
    const int m   = t >> 2;
    const int pix = t & 3;
    const float s = (Pp[(0 * NPIXB + pix) * NM + m] +
                     Pp[(1 * NPIXB + pix) * NM + m]) +
                    (Pp[(2 * NPIXB + pix) * NM + m] +
                     Pp[(3 * NPIXB + pix) * NM + m]);
    out[(size_t)m * NPIXT + p * RES + q0 + pix] = s;
  }
}

extern "C" void kernel_launch(void* const* d_in, const int* in_sizes, int n_in,
                              void* d_out, int out_size, void* d_ws, size_t ws_size,
                              hipStream_t stream) {
  const float* p_inc   = (const float*)d_in[0];
  const float* p_rot   = (const float*)d_in[1];
  const float* p_lb    = (const float*)d_in[2];
  const float* p_vs    = (const float*)d_in[3];
  const float* p_vmax  = (const float*)d_in[4];
  const float* p_rturn = (const float*)d_in[5];
  const float* p_i0    = (const float*)d_in[6];
  const float* p_rd    = (const float*)d_in[7];
  const float* freqs   = (const float*)d_in[8];
  float* out = (float*)d_out;
  float* ws  = (float*)d_ws;
  float* h   = (float*)((char*)d_ws + H_OFF);

  if (ws_size >= WS_REQ) {
    hipLaunchKernelGGL(gtable_kernel, dim3((NB * NM + 255) / 256), dim3(256),
                       0, stream, p_inc, p_rot, p_lb, p_vs, p_vmax, p_rturn,
                       p_i0, p_rd, freqs, ws);
    hipLaunchKernelGGL(deposit2x_kernel, dim3(NPIXT / NPIXB), dim3(256),
                       0, stream, ws, h);
    hipLaunchKernelGGL(matvec_kernel, dim3(NPIXT / NPIXB), dim3(256),
                       0, stream, ws, h, out);
  } else {
    hipLaunchKernelGGL(fused_self_kernel, dim3(NPIXT / NPIXB), dim3(256),
                       0, stream, p_inc, p_rot, p_lb, p_vs, p_vmax, p_rturn,
                       p_i0, p_rd, freqs, out);
  }
}